// Round 1
// baseline (327.187 us; speedup 1.0000x reference)
//
#include <hip/hip_runtime.h>

constexpr int B = 8;
constexpr int C = 512;
constexpr int M = 64;
constexpr int N = 4096;
constexpr float EPS = 1e-6f;

// ---------------------------------------------------------------------------
// LDS tile loader: 64x64 f32 tile, rows padded to 68 floats (272B, 16B-aligned
// so float4 writes are legal; 68%32=4 keeps hot read patterns <=2-way banked).
// ---------------------------------------------------------------------------
__device__ __forceinline__ void load_tile68(const float* __restrict__ g, int stride,
                                            float* __restrict__ lds, int t) {
#pragma unroll
  for (int i = 0; i < 4; ++i) {
    const int id = t + (i << 8);
    const int r = id >> 4;
    const int c4 = (id & 15) << 2;
    const float4 v = *reinterpret_cast<const float4*>(g + (size_t)r * stride + c4);
    *reinterpret_cast<float4*>(lds + r * 68 + c4) = v;
  }
}

// ---------------------------------------------------------------------------
// Prep: transpose Wq,Wk -> [C][M], Wv -> [C'][C] once (coalesced writes; the
// strided reads are tiny and L2-absorbed).
// ---------------------------------------------------------------------------
__global__ __launch_bounds__(256) void prep_kernel(
    const float* __restrict__ Wq, const float* __restrict__ Wk,
    const float* __restrict__ Wv, float* __restrict__ WqT,
    float* __restrict__ WkT, float* __restrict__ WvT) {
  const int id = blockIdx.x * 256 + threadIdx.x;
  if (id < C * M) {
    const int c = id / M, m = id % M;
    WqT[id] = Wq[m * C + c];
    WkT[id] = Wk[m * C + c];
  }
  for (int k = id; k < C * C; k += gridDim.x * 256) {
    const int cp = k / C, c = k % C;
    WvT[k] = Wv[c * C + cp];  // WvT[c'][c]
  }
}

// ---------------------------------------------------------------------------
// Q/K channel GEMM + per-position L2 normalize. Block = 64 n-cols x all 64 m.
// ---------------------------------------------------------------------------
__global__ __launch_bounds__(256) void qk_kernel(
    const float* __restrict__ x, const float* __restrict__ WqT,
    const float* __restrict__ bq, const float* __restrict__ WkT,
    const float* __restrict__ bk, float* __restrict__ Qn, float* __restrict__ Kn) {
  __shared__ float xs[64 * 68];
  __shared__ float wqs[64 * 68];
  __shared__ float wks[64 * 68];
  const int t = threadIdx.x;
  const int n0 = blockIdx.x * 64;
  const int b = blockIdx.y;
  const int tn = (t & 15) << 2;  // n sub-tile base
  const int tm = (t >> 4) << 2;  // m sub-tile base
  float qa[4][4] = {};
  float ka[4][4] = {};
  for (int c0 = 0; c0 < C; c0 += 64) {
    __syncthreads();
    load_tile68(x + ((size_t)b * C + c0) * N + n0, N, xs, t);   // xs[c][n]
    load_tile68(WqT + (size_t)c0 * M, M, wqs, t);               // wqs[c][m]
    load_tile68(WkT + (size_t)c0 * M, M, wks, t);               // wks[c][m]
    __syncthreads();
#pragma unroll 4
    for (int cc = 0; cc < 64; ++cc) {
      const float4 xv = *reinterpret_cast<const float4*>(xs + cc * 68 + tn);
      const float4 wq = *reinterpret_cast<const float4*>(wqs + cc * 68 + tm);
      const float4 wk = *reinterpret_cast<const float4*>(wks + cc * 68 + tm);
      const float xvv[4] = {xv.x, xv.y, xv.z, xv.w};
      const float wqv[4] = {wq.x, wq.y, wq.z, wq.w};
      const float wkv[4] = {wk.x, wk.y, wk.z, wk.w};
#pragma unroll
      for (int im = 0; im < 4; ++im)
#pragma unroll
        for (int in = 0; in < 4; ++in) {
          qa[im][in] = fmaf(wqv[im], xvv[in], qa[im][in]);
          ka[im][in] = fmaf(wkv[im], xvv[in], ka[im][in]);
        }
    }
  }
#pragma unroll
  for (int im = 0; im < 4; ++im) {
    const float bqv = bq[tm + im], bkv = bk[tm + im];
#pragma unroll
    for (int in = 0; in < 4; ++in) { qa[im][in] += bqv; ka[im][in] += bkv; }
  }
  __syncthreads();
  // per-column (n) sum of squares over m, via [16 m-groups][64 n] partials
  float* redq = wqs;
  float* redk = wqs + 16 * 68;
  {
    float pq[4] = {}, pk[4] = {};
#pragma unroll
    for (int im = 0; im < 4; ++im)
#pragma unroll
      for (int in = 0; in < 4; ++in) {
        pq[in] = fmaf(qa[im][in], qa[im][in], pq[in]);
        pk[in] = fmaf(ka[im][in], ka[im][in], pk[in]);
      }
    const int g = t >> 4;
#pragma unroll
    for (int in = 0; in < 4; ++in) {
      redq[g * 68 + tn + in] = pq[in];
      redk[g * 68 + tn + in] = pk[in];
    }
  }
  __syncthreads();
  float* rnq = wks;
  float* rnk = wks + 64;
  if (t < 64) {
    float sq = 0.f, sk = 0.f;
#pragma unroll
    for (int g = 0; g < 16; ++g) { sq += redq[g * 68 + t]; sk += redk[g * 68 + t]; }
    rnq[t] = 1.0f / sqrtf(sq);
    rnk[t] = 1.0f / sqrtf(sk);
  }
  __syncthreads();
  const size_t obase = (size_t)b * M * N + n0;
#pragma unroll
  for (int im = 0; im < 4; ++im) {
    const int m = tm + im;
    float4 q4, k4;
    q4.x = qa[im][0] * rnq[tn + 0]; q4.y = qa[im][1] * rnq[tn + 1];
    q4.z = qa[im][2] * rnq[tn + 2]; q4.w = qa[im][3] * rnq[tn + 3];
    k4.x = ka[im][0] * rnk[tn + 0]; k4.y = ka[im][1] * rnk[tn + 1];
    k4.z = ka[im][2] * rnk[tn + 2]; k4.w = ka[im][3] * rnk[tn + 3];
    *reinterpret_cast<float4*>(Qn + obase + (size_t)m * N + tn) = q4;
    *reinterpret_cast<float4*>(Kn + obase + (size_t)m * N + tn) = k4;
  }
}

// ---------------------------------------------------------------------------
// Generic row sum over N=4096 contiguous floats. Used for xsum and Ksum.
// ---------------------------------------------------------------------------
__global__ __launch_bounds__(256) void rowsum_kernel(const float* __restrict__ src,
                                                     float* __restrict__ dst) {
  const int r = blockIdx.x;
  const float* row = src + (size_t)r * N;
  const int t = threadIdx.x;
  float s = 0.f;
  for (int i = t * 4; i < N; i += 1024) {
    const float4 v = *reinterpret_cast<const float4*>(row + i);
    s += v.x + v.y + v.z + v.w;
  }
#pragma unroll
  for (int off = 32; off > 0; off >>= 1) s += __shfl_down(s, off, 64);
  __shared__ float rb[4];
  if ((t & 63) == 0) rb[t >> 6] = s;
  __syncthreads();
  if (t == 0) dst[r] = rb[0] + rb[1] + rb[2] + rb[3];
}

// ---------------------------------------------------------------------------
// S[c',m] = sum_n x[c',n] * Kn[m,n]; 4-way n-split into Spart[nt][b][c'][m].
// ---------------------------------------------------------------------------
__global__ __launch_bounds__(256) void s_kernel(const float* __restrict__ x,
                                                const float* __restrict__ Kn,
                                                float* __restrict__ Spart) {
  __shared__ float xs[64 * 68];  // [c'][nn]
  __shared__ float ks[64 * 68];  // [m][nn]
  const int t = threadIdx.x;
  const int c0 = blockIdx.x * 64;
  const int nt = blockIdx.y;
  const int b = blockIdx.z;
  const int tmc = (t >> 4) << 2;  // c' rows
  const int tmm = (t & 15) << 2;  // m rows
  float acc[4][4] = {};           // [ic][im]
  for (int n0 = nt * 1024; n0 < (nt + 1) * 1024; n0 += 64) {
    __syncthreads();
    load_tile68(x + ((size_t)b * C + c0) * N + n0, N, xs, t);
    load_tile68(Kn + (size_t)b * M * N + n0, N, ks, t);
    __syncthreads();
#pragma unroll 4
    for (int nn = 0; nn < 64; nn += 4) {
      float4 xv[4], kv[4];
#pragma unroll
      for (int i = 0; i < 4; ++i)
        xv[i] = *reinterpret_cast<const float4*>(xs + (tmc + i) * 68 + nn);
#pragma unroll
      for (int i = 0; i < 4; ++i)
        kv[i] = *reinterpret_cast<const float4*>(ks + (tmm + i) * 68 + nn);
#pragma unroll
      for (int ic = 0; ic < 4; ++ic)
#pragma unroll
        for (int im = 0; im < 4; ++im) {
          float a = acc[ic][im];
          a = fmaf(xv[ic].x, kv[im].x, a);
          a = fmaf(xv[ic].y, kv[im].y, a);
          a = fmaf(xv[ic].z, kv[im].z, a);
          a = fmaf(xv[ic].w, kv[im].w, a);
          acc[ic][im] = a;
        }
    }
  }
  float* outp = Spart + (size_t)nt * B * C * M + ((size_t)b * C + c0) * M;
#pragma unroll
  for (int ic = 0; ic < 4; ++ic) {
    float4 o = {acc[ic][0], acc[ic][1], acc[ic][2], acc[ic][3]};
    *reinterpret_cast<float4*>(outp + (size_t)(tmc + ic) * M + tmm) = o;
  }
}

// ---------------------------------------------------------------------------
// matM[b][m][c] = sum_c' Wv[c][c'] S[c'][m] + bv[c]*Ksum[m]
// vsum[b][c]    = sum_c' Wv[c][c'] xsum[c'] + N*bv[c]
// ---------------------------------------------------------------------------
__global__ __launch_bounds__(256) void matm_kernel(
    const float* __restrict__ WvT, const float* __restrict__ bv,
    const float* __restrict__ Spart, const float* __restrict__ xsum,
    const float* __restrict__ Ksum, float* __restrict__ matM,
    float* __restrict__ vsum) {
  __shared__ float wvs[64 * 68];  // [c'][c]
  __shared__ float ss[64 * 68];   // [c'][m]
  __shared__ float xss[64];
  const int t = threadIdx.x;
  const int c0 = blockIdx.x * 64;
  const int b = blockIdx.y;
  const int tmm = (t >> 4) << 2;  // m rows
  const int tnc = (t & 15) << 2;  // c cols
  float acc[4][4] = {};           // [im][icc]
  float vacc = 0.f;
  for (int k0 = 0; k0 < C; k0 += 64) {
    __syncthreads();
    load_tile68(WvT + (size_t)k0 * C + c0, C, wvs, t);
#pragma unroll
    for (int i = 0; i < 4; ++i) {  // ss = sum of 4 n-partials
      const int id = t + (i << 8);
      const int r = id >> 4;
      const int c4 = (id & 15) << 2;
      const float* p = Spart + ((size_t)b * C + k0 + r) * M + c4;
      const float4 v0 = *reinterpret_cast<const float4*>(p);
      const float4 v1 = *reinterpret_cast<const float4*>(p + (size_t)B * C * M);
      const float4 v2 = *reinterpret_cast<const float4*>(p + 2 * (size_t)B * C * M);
      const float4 v3 = *reinterpret_cast<const float4*>(p + 3 * (size_t)B * C * M);
      float4 v;
      v.x = v0.x + v1.x + v2.x + v3.x;
      v.y = v0.y + v1.y + v2.y + v3.y;
      v.z = v0.z + v1.z + v2.z + v3.z;
      v.w = v0.w + v1.w + v2.w + v3.w;
      *reinterpret_cast<float4*>(ss + r * 68 + c4) = v;
    }
    if (t < 64) xss[t] = xsum[b * C + k0 + t];
    __syncthreads();
#pragma unroll 4
    for (int kk = 0; kk < 64; ++kk) {
      const float4 sv = *reinterpret_cast<const float4*>(ss + kk * 68 + tmm);
      const float4 wv = *reinterpret_cast<const float4*>(wvs + kk * 68 + tnc);
      const float svv[4] = {sv.x, sv.y, sv.z, sv.w};
      const float wvv[4] = {wv.x, wv.y, wv.z, wv.w};
#pragma unroll
      for (int im = 0; im < 4; ++im)
#pragma unroll
        for (int icc = 0; icc < 4; ++icc)
          acc[im][icc] = fmaf(svv[im], wvv[icc], acc[im][icc]);
    }
    if (t < 64) {
      float v = 0.f;
#pragma unroll 8
      for (int kk = 0; kk < 64; ++kk) v = fmaf(wvs[kk * 68 + t], xss[kk], v);
      vacc += v;
    }
  }
  float bvv[4];
#pragma unroll
  for (int icc = 0; icc < 4; ++icc) bvv[icc] = bv[c0 + tnc + icc];
#pragma unroll
  for (int im = 0; im < 4; ++im) {
    const float ksv = Ksum[b * M + tmm + im];
    float4 o;
    o.x = acc[im][0] + bvv[0] * ksv;
    o.y = acc[im][1] + bvv[1] * ksv;
    o.z = acc[im][2] + bvv[2] * ksv;
    o.w = acc[im][3] + bvv[3] * ksv;
    *reinterpret_cast<float4*>(matM + ((size_t)b * M + tmm + im) * C + c0 + tnc) = o;
  }
  if (t < 64) vsum[b * C + c0 + t] = vacc + 4096.0f * bv[c0 + t];
}

// ---------------------------------------------------------------------------
// out[c,n] = x[c,n] + g * tailor[n] * (vsum[c] + sum_m matM[m][c]*Qn[m][n])
// tailor[n] = 1/(N + sum_m Qn[m][n]*(Ksum[m]+EPS))
// ---------------------------------------------------------------------------
__global__ __launch_bounds__(256) void final_kernel(
    const float* __restrict__ x, const float* __restrict__ Qn,
    const float* __restrict__ Ksum, const float* __restrict__ matM,
    const float* __restrict__ vsum, const float* __restrict__ gamma,
    float* __restrict__ out) {
  __shared__ float qs[64 * 68];  // [m][n]
  __shared__ float mt[64 * 68];  // [m][c-chunk]
  __shared__ float ke[64];
  __shared__ float tl[64];
  const int t = threadIdx.x;
  const int n0 = blockIdx.x * 64;
  const int b = blockIdx.y;
  const int tn = (t & 15) << 2;  // n cols
  const int tc = (t >> 4) << 2;  // c rows
  load_tile68(Qn + (size_t)b * M * N + n0, N, qs, t);
  if (t < 64) ke[t] = Ksum[b * M + t] + EPS;
  __syncthreads();
  if (t < 64) {
    float d = 0.f;
#pragma unroll 8
    for (int m = 0; m < 64; ++m) d = fmaf(qs[m * 68 + t], ke[m], d);
    tl[t] = 1.0f / (4096.0f + d);
  }
  const float g = gamma[0];
  for (int c0 = 0; c0 < C; c0 += 64) {
    __syncthreads();
    load_tile68(matM + (size_t)b * M * C + c0, C, mt, t);
    __syncthreads();
    float acc[4][4] = {};  // [ic][in]
#pragma unroll 4
    for (int m = 0; m < 64; ++m) {
      const float4 qv = *reinterpret_cast<const float4*>(qs + m * 68 + tn);
      const float4 mv = *reinterpret_cast<const float4*>(mt + m * 68 + tc);
      const float qvv[4] = {qv.x, qv.y, qv.z, qv.w};
      const float mvv[4] = {mv.x, mv.y, mv.z, mv.w};
#pragma unroll
      for (int ic = 0; ic < 4; ++ic)
#pragma unroll
        for (int in = 0; in < 4; ++in)
          acc[ic][in] = fmaf(mvv[ic], qvv[in], acc[ic][in]);
    }
#pragma unroll
    for (int ic = 0; ic < 4; ++ic) {
      const int c = c0 + tc + ic;
      const float vs = vsum[b * C + c];
      const size_t off = ((size_t)b * C + c) * N + n0 + tn;
      const float4 xv = *reinterpret_cast<const float4*>(x + off);
      float4 o;
      o.x = xv.x + g * tl[tn + 0] * (vs + acc[ic][0]);
      o.y = xv.y + g * tl[tn + 1] * (vs + acc[ic][1]);
      o.z = xv.z + g * tl[tn + 2] * (vs + acc[ic][2]);
      o.w = xv.w + g * tl[tn + 3] * (vs + acc[ic][3]);
      *reinterpret_cast<float4*>(out + off) = o;
    }
  }
}

// ---------------------------------------------------------------------------
extern "C" void kernel_launch(void* const* d_in, const int* in_sizes, int n_in,
                              void* d_out, int out_size, void* d_ws, size_t ws_size,
                              hipStream_t stream) {
  (void)in_sizes; (void)n_in; (void)out_size; (void)ws_size;
  const float* x = (const float*)d_in[0];
  const float* Wq = (const float*)d_in[1];
  const float* bq = (const float*)d_in[2];
  const float* Wk = (const float*)d_in[3];
  const float* bk = (const float*)d_in[4];
  const float* Wv = (const float*)d_in[5];
  const float* bv = (const float*)d_in[6];
  const float* gamma = (const float*)d_in[7];
  float* out = (float*)d_out;

  // ws layout (floats) — total ~23.4 MB
  float* ws = (float*)d_ws;
  float* WqT = ws;                          // C*M
  float* WkT = WqT + (size_t)C * M;         // C*M
  float* WvT = WkT + (size_t)C * M;         // C*C
  float* Spart = WvT + (size_t)C * C;       // 4*B*C*M
  float* Qn = Spart + 4 * (size_t)B * C * M;  // B*M*N
  float* Kn = Qn + (size_t)B * M * N;       // B*M*N
  float* Ksum = Kn + (size_t)B * M * N;     // B*M
  float* xsum = Ksum + B * M;               // B*C
  float* vsum = xsum + B * C;               // B*C
  float* matM = vsum + B * C;               // B*M*C

  prep_kernel<<<1024, 256, 0, stream>>>(Wq, Wk, Wv, WqT, WkT, WvT);
  qk_kernel<<<dim3(N / 64, B), 256, 0, stream>>>(x, WqT, bq, WkT, bk, Qn, Kn);
  rowsum_kernel<<<B * C, 256, 0, stream>>>(x, xsum);
  rowsum_kernel<<<B * M, 256, 0, stream>>>(Kn, Ksum);
  s_kernel<<<dim3(C / 64, 4, B), 256, 0, stream>>>(x, Kn, Spart);
  matm_kernel<<<dim3(C / 64, B), 256, 0, stream>>>(WvT, bv, Spart, xsum, Ksum, matM, vsum);
  final_kernel<<<dim3(N / 64, B), 256, 0, stream>>>(x, Qn, Ksum, matM, vsum, gamma, out);
}

// Round 4
// 317.731 us; speedup vs baseline: 1.0298x; 1.0298x over previous
//
#include <hip/hip_runtime.h>

constexpr int B = 8;
constexpr int C = 512;
constexpr int M = 64;
constexpr int N = 4096;
constexpr float EPS = 1e-6f;
constexpr int NT = 16;  // n-split for s_kernel -> 8*16*8 = 1024 blocks

// ---------------------------------------------------------------------------
// LDS tile loader: 64x64 f32 tile, rows padded to 68 floats.
// ---------------------------------------------------------------------------
__device__ __forceinline__ void load_tile68(const float* __restrict__ g, int stride,
                                            float* __restrict__ lds, int t) {
#pragma unroll
  for (int i = 0; i < 4; ++i) {
    const int id = t + (i << 8);
    const int r = id >> 4;
    const int c4 = (id & 15) << 2;
    const float4 v = *reinterpret_cast<const float4*>(g + (size_t)r * stride + c4);
    *reinterpret_cast<float4*>(lds + r * 68 + c4) = v;
  }
}

// ---------------------------------------------------------------------------
// Prep: transpose weights + zero the accumulation region [S|matM|xsum|Ksum|vsum].
// ---------------------------------------------------------------------------
__global__ __launch_bounds__(256) void prep_kernel(
    const float* __restrict__ Wq, const float* __restrict__ Wk,
    const float* __restrict__ Wv, float* __restrict__ WqT,
    float* __restrict__ WkT, float* __restrict__ WvT,
    float* __restrict__ zbase, int zcount) {
  const int id = blockIdx.x * 256 + threadIdx.x;
  if (id < C * M) {
    const int c = id / M, m = id % M;
    WqT[id] = Wq[m * C + c];
    WkT[id] = Wk[m * C + c];
  }
  const int stride = gridDim.x * 256;
  for (int k = id; k < C * C; k += stride) {
    const int cp = k / C, c = k % C;
    WvT[k] = Wv[c * C + cp];  // WvT[c'][c]
  }
  for (int k = id; k < zcount; k += stride) zbase[k] = 0.f;
}

// ---------------------------------------------------------------------------
// Q/K channel GEMM + L2 normalize. Writes Qn[b][m][n], KnT[b][n][m]; fuses
// Ksum[b][m] = sum_n Kn via shfl-reduce + atomics.
// ---------------------------------------------------------------------------
__global__ __launch_bounds__(256) void qk_kernel(
    const float* __restrict__ x, const float* __restrict__ WqT,
    const float* __restrict__ bq, const float* __restrict__ WkT,
    const float* __restrict__ bk, float* __restrict__ Qn,
    float* __restrict__ KnT, float* __restrict__ Ksum) {
  __shared__ float xs[64 * 68];
  __shared__ float wqs[64 * 68];
  __shared__ float wks[64 * 68];
  const int t = threadIdx.x;
  const int n0 = blockIdx.x * 64;
  const int b = blockIdx.y;
  const int tn = (t & 15) << 2;  // n sub-tile base
  const int tm = (t >> 4) << 2;  // m sub-tile base
  float qa[4][4] = {};
  float ka[4][4] = {};
  for (int c0 = 0; c0 < C; c0 += 64) {
    __syncthreads();
    load_tile68(x + ((size_t)b * C + c0) * N + n0, N, xs, t);  // xs[c][n]
    load_tile68(WqT + (size_t)c0 * M, M, wqs, t);              // wqs[c][m]
    load_tile68(WkT + (size_t)c0 * M, M, wks, t);              // wks[c][m]
    __syncthreads();
#pragma unroll 4
    for (int cc = 0; cc < 64; ++cc) {
      const float4 xv = *reinterpret_cast<const float4*>(xs + cc * 68 + tn);
      const float4 wq = *reinterpret_cast<const float4*>(wqs + cc * 68 + tm);
      const float4 wk = *reinterpret_cast<const float4*>(wks + cc * 68 + tm);
      const float xvv[4] = {xv.x, xv.y, xv.z, xv.w};
      const float wqv[4] = {wq.x, wq.y, wq.z, wq.w};
      const float wkv[4] = {wk.x, wk.y, wk.z, wk.w};
#pragma unroll
      for (int im = 0; im < 4; ++im)
#pragma unroll
        for (int in = 0; in < 4; ++in) {
          qa[im][in] = fmaf(wqv[im], xvv[in], qa[im][in]);
          ka[im][in] = fmaf(wkv[im], xvv[in], ka[im][in]);
        }
    }
  }
#pragma unroll
  for (int im = 0; im < 4; ++im) {
    const float bqv = bq[tm + im], bkv = bk[tm + im];
#pragma unroll
    for (int in = 0; in < 4; ++in) { qa[im][in] += bqv; ka[im][in] += bkv; }
  }
  __syncthreads();
  // per-position (n) sum of squares over m: [16 m-groups][64 n] partials
  float* redq = wqs;
  float* redk = wqs + 16 * 68;
  {
    float pq[4] = {}, pk[4] = {};
#pragma unroll
    for (int im = 0; im < 4; ++im)
#pragma unroll
      for (int in = 0; in < 4; ++in) {
        pq[in] = fmaf(qa[im][in], qa[im][in], pq[in]);
        pk[in] = fmaf(ka[im][in], ka[im][in], pk[in]);
      }
    const int g = t >> 4;
#pragma unroll
    for (int in = 0; in < 4; ++in) {
      redq[g * 68 + tn + in] = pq[in];
      redk[g * 68 + tn + in] = pk[in];
    }
  }
  __syncthreads();
  float* rnq = wks;
  float* rnk = wks + 64;
  if (t < 64) {
    float sq = 0.f, sk = 0.f;
#pragma unroll
    for (int g = 0; g < 16; ++g) { sq += redq[g * 68 + t]; sk += redk[g * 68 + t]; }
    rnq[t] = 1.0f / sqrtf(sq);
    rnk[t] = 1.0f / sqrtf(sk);
  }
  __syncthreads();
  // normalized values
  float kn[4][4];  // [im][in]
  const size_t qbase = (size_t)b * M * N + n0;
#pragma unroll
  for (int im = 0; im < 4; ++im) {
    float4 q4;
    q4.x = qa[im][0] * rnq[tn + 0]; q4.y = qa[im][1] * rnq[tn + 1];
    q4.z = qa[im][2] * rnq[tn + 2]; q4.w = qa[im][3] * rnq[tn + 3];
    *reinterpret_cast<float4*>(Qn + qbase + (size_t)(tm + im) * N + tn) = q4;
#pragma unroll
    for (int in = 0; in < 4; ++in) kn[im][in] = ka[im][in] * rnk[tn + in];
  }
  // KnT[b][n][m] write: row n = n0+tn+in, cols tm..tm+3
  const size_t ktbase = ((size_t)b * N + n0) * M;
#pragma unroll
  for (int in = 0; in < 4; ++in) {
    float4 k4 = {kn[0][in], kn[1][in], kn[2][in], kn[3][in]};
    *reinterpret_cast<float4*>(KnT + ktbase + (size_t)(tn + in) * M + tm) = k4;
  }
  // Ksum: reduce each m-row partial over the 16 lanes sharing tm (low 4 lane bits)
#pragma unroll
  for (int im = 0; im < 4; ++im) {
    float s = kn[im][0] + kn[im][1] + kn[im][2] + kn[im][3];
#pragma unroll
    for (int off = 1; off < 16; off <<= 1) s += __shfl_xor(s, off, 64);
    if ((t & 15) == 0) atomicAdd(&Ksum[b * M + tm + im], s);
  }
}

// ---------------------------------------------------------------------------
// S[b][c'][m] += sum_n x[c',n]*Kn[m,n] over this block's n-range; fuses
// xsum[b][c'] += sum_n x[c',n]. Conflict-free: ks is [n][m] so both GEMM
// reads are row-uniform across lanes.
// ---------------------------------------------------------------------------
__global__ __launch_bounds__(256) void s_kernel(const float* __restrict__ x,
                                                const float* __restrict__ KnT,
                                                float* __restrict__ S,
                                                float* __restrict__ xsum) {
  __shared__ float xs[64 * 68];  // [c'][n]
  __shared__ float ks[64 * 68];  // [n][m]
  __shared__ float red[256];
  const int t = threadIdx.x;
  const int c0 = blockIdx.x * 64;
  const int nt = blockIdx.y;
  const int b = blockIdx.z;
  const int tmc = (t >> 4) << 2;  // c' rows (4 groups -> 2-way, free)
  const int tmm = (t & 15) << 2;  // m cols (row-uniform reads, free)
  const int rr = t & 63, q = t >> 6;
  float acc[4][4] = {};  // [ic][im]
  float xacc = 0.f;
  for (int it = 0; it < N / NT / 64; ++it) {
    const int n0 = nt * (N / NT) + it * 64;
    __syncthreads();
    load_tile68(x + ((size_t)b * C + c0) * N + n0, N, xs, t);
    load_tile68(KnT + ((size_t)b * N + n0) * M, M, ks, t);
    __syncthreads();
#pragma unroll 2
    for (int nn = 0; nn < 64; nn += 4) {
      float xvv[4][4];
#pragma unroll
      for (int ic = 0; ic < 4; ++ic) {
        const float4 v = *reinterpret_cast<const float4*>(xs + (tmc + ic) * 68 + nn);
        xvv[ic][0] = v.x; xvv[ic][1] = v.y; xvv[ic][2] = v.z; xvv[ic][3] = v.w;
      }
#pragma unroll
      for (int j = 0; j < 4; ++j) {
        const float4 kv = *reinterpret_cast<const float4*>(ks + (nn + j) * 68 + tmm);
        const float kvv[4] = {kv.x, kv.y, kv.z, kv.w};
#pragma unroll
        for (int ic = 0; ic < 4; ++ic)
#pragma unroll
          for (int im = 0; im < 4; ++im)
            acc[ic][im] = fmaf(xvv[ic][j], kvv[im], acc[ic][im]);
      }
    }
    // xsum partial: thread (rr, q) sums its quarter of row rr
#pragma unroll
    for (int k2 = 0; k2 < 4; ++k2) {
      const float4 v = *reinterpret_cast<const float4*>(xs + rr * 68 + q * 16 + k2 * 4);
      xacc += v.x + v.y + v.z + v.w;
    }
  }
  red[q * 64 + rr] = xacc;
  __syncthreads();
  if (t < 64) {
    const float s = red[t] + red[64 + t] + red[128 + t] + red[192 + t];
    atomicAdd(&xsum[b * C + c0 + t], s);
  }
#pragma unroll
  for (int ic = 0; ic < 4; ++ic)
#pragma unroll
    for (int im = 0; im < 4; ++im)
      atomicAdd(&S[((size_t)b * C + c0 + tmc + ic) * M + tmm + im], acc[ic][im]);
}

// ---------------------------------------------------------------------------
// matM[b][m][c] += sum_{k in range} Wv[c][k] S[k][m]  (+ bv[c]*Ksum[m] on ky==0)
// vsum[b][c]    += sum_{k in range} Wv[c][k] xsum[k]  (+ N*bv[c] on ky==0)
// k-split x4 for parallelism.
// ---------------------------------------------------------------------------
__global__ __launch_bounds__(256) void matm_kernel(
    const float* __restrict__ WvT, const float* __restrict__ bv,
    const float* __restrict__ S, const float* __restrict__ xsum,
    const float* __restrict__ Ksum, float* __restrict__ matM,
    float* __restrict__ vsum) {
  __shared__ float wvs[64 * 68];  // [k][c]
  __shared__ float ss[64 * 68];   // [k][m]
  __shared__ float xss[64];
  const int t = threadIdx.x;
  const int c0 = blockIdx.x * 64;
  const int ky = blockIdx.y;
  const int b = blockIdx.z;
  const int tmm = (t >> 4) << 2;  // m rows
  const int tnc = (t & 15) << 2;  // c cols
  float acc[4][4] = {};           // [im][icc]
  float vacc = 0.f;
  for (int kc = 0; kc < 2; ++kc) {
    const int k0 = ky * 128 + kc * 64;
    __syncthreads();
    load_tile68(WvT + (size_t)k0 * C + c0, C, wvs, t);
    load_tile68(S + ((size_t)b * C + k0) * M, M, ss, t);
    if (t < 64) xss[t] = xsum[b * C + k0 + t];
    __syncthreads();
#pragma unroll 4
    for (int kk = 0; kk < 64; ++kk) {
      const float4 sv = *reinterpret_cast<const float4*>(ss + kk * 68 + tmm);
      const float4 wv = *reinterpret_cast<const float4*>(wvs + kk * 68 + tnc);
      const float svv[4] = {sv.x, sv.y, sv.z, sv.w};
      const float wvv[4] = {wv.x, wv.y, wv.z, wv.w};
#pragma unroll
      for (int im = 0; im < 4; ++im)
#pragma unroll
        for (int icc = 0; icc < 4; ++icc)
          acc[im][icc] = fmaf(svv[im], wvv[icc], acc[im][icc]);
    }
    if (t < 64) {
      float v = 0.f;
#pragma unroll 8
      for (int kk = 0; kk < 64; ++kk) v = fmaf(wvs[kk * 68 + t], xss[kk], v);
      vacc += v;
    }
  }
  float bvv[4];
#pragma unroll
  for (int icc = 0; icc < 4; ++icc) bvv[icc] = bv[c0 + tnc + icc];
#pragma unroll
  for (int im = 0; im < 4; ++im) {
    const float ksv = (ky == 0) ? Ksum[b * M + tmm + im] : 0.f;
#pragma unroll
    for (int icc = 0; icc < 4; ++icc)
      atomicAdd(&matM[((size_t)b * M + tmm + im) * C + c0 + tnc + icc],
                acc[im][icc] + bvv[icc] * ksv);
  }
  if (t < 64)
    atomicAdd(&vsum[b * C + c0 + t], vacc + (ky == 0 ? 4096.0f * bv[c0 + t] : 0.f));
}

// ---------------------------------------------------------------------------
// out[c,n] = x[c,n] + g * tailor[n] * (vsum[c] + sum_m matM[m][c]*Qn[m][n])
// c-split x2 for occupancy.
// ---------------------------------------------------------------------------
__global__ __launch_bounds__(256) void final_kernel(
    const float* __restrict__ x, const float* __restrict__ Qn,
    const float* __restrict__ Ksum, const float* __restrict__ matM,
    const float* __restrict__ vsum, const float* __restrict__ gamma,
    float* __restrict__ out) {
  __shared__ float qs[64 * 68];  // [m][n]
  __shared__ float mt[64 * 68];  // [m][c-chunk]
  __shared__ float ke[64];
  __shared__ float tl[64];
  const int t = threadIdx.x;
  const int n0 = blockIdx.x * 64;
  const int cy = blockIdx.y;
  const int b = blockIdx.z;
  const int tn = (t & 15) << 2;  // n cols
  const int tc = (t >> 4) << 2;  // c rows
  load_tile68(Qn + (size_t)b * M * N + n0, N, qs, t);
  if (t < 64) ke[t] = Ksum[b * M + t] + EPS;
  __syncthreads();
  if (t < 64) {
    float d = 0.f;
#pragma unroll 8
    for (int m = 0; m < 64; ++m) d = fmaf(qs[m * 68 + t], ke[m], d);
    tl[t] = 1.0f / (4096.0f + d);
  }
  const float g = gamma[0];
  for (int cc = 0; cc < 4; ++cc) {
    const int c0 = cy * 256 + cc * 64;
    __syncthreads();
    load_tile68(matM + (size_t)b * M * C + c0, C, mt, t);
    __syncthreads();
    float acc[4][4] = {};  // [ic][in]
#pragma unroll 4
    for (int m = 0; m < 64; ++m) {
      const float4 qv = *reinterpret_cast<const float4*>(qs + m * 68 + tn);
      const float4 mv = *reinterpret_cast<const float4*>(mt + m * 68 + tc);
      const float qvv[4] = {qv.x, qv.y, qv.z, qv.w};
      const float mvv[4] = {mv.x, mv.y, mv.z, mv.w};
#pragma unroll
      for (int ic = 0; ic < 4; ++ic)
#pragma unroll
        for (int in = 0; in < 4; ++in)
          acc[ic][in] = fmaf(mvv[ic], qvv[in], acc[ic][in]);
    }
#pragma unroll
    for (int ic = 0; ic < 4; ++ic) {
      const int c = c0 + tc + ic;
      const float vs = vsum[b * C + c];
      const size_t off = ((size_t)b * C + c) * N + n0 + tn;
      const float4 xv = *reinterpret_cast<const float4*>(x + off);
      float4 o;
      o.x = xv.x + g * tl[tn + 0] * (vs + acc[ic][0]);
      o.y = xv.y + g * tl[tn + 1] * (vs + acc[ic][1]);
      o.z = xv.z + g * tl[tn + 2] * (vs + acc[ic][2]);
      o.w = xv.w + g * tl[tn + 3] * (vs + acc[ic][3]);
      *reinterpret_cast<float4*>(out + off) = o;
    }
  }
}

// ---------------------------------------------------------------------------
extern "C" void kernel_launch(void* const* d_in, const int* in_sizes, int n_in,
                              void* d_out, int out_size, void* d_ws, size_t ws_size,
                              hipStream_t stream) {
  (void)in_sizes; (void)n_in; (void)out_size; (void)ws_size;
  const float* x = (const float*)d_in[0];
  const float* Wq = (const float*)d_in[1];
  const float* bq = (const float*)d_in[2];
  const float* Wk = (const float*)d_in[3];
  const float* bk = (const float*)d_in[4];
  const float* Wv = (const float*)d_in[5];
  const float* bv = (const float*)d_in[6];
  const float* gamma = (const float*)d_in[7];
  float* out = (float*)d_out;

  // ws layout (floats), ~20.2 MB total
  float* ws = (float*)d_ws;
  float* WqT = ws;                            // C*M
  float* WkT = WqT + (size_t)C * M;           // C*M
  float* WvT = WkT + (size_t)C * M;           // C*C
  float* Qn = WvT + (size_t)C * C;            // B*M*N
  float* KnT = Qn + (size_t)B * M * N;        // B*N*M
  float* S = KnT + (size_t)B * N * M;         // B*C*M   (zero region start)
  float* matM = S + (size_t)B * C * M;        // B*M*C
  float* xsum = matM + (size_t)B * M * C;     // B*C
  float* Ksum = xsum + (size_t)B * C;         // B*M
  float* vsum = Ksum + (size_t)B * M;         // B*C
  const int zcount = B * C * M + B * M * C + B * C + B * M + B * C;

  prep_kernel<<<1024, 256, 0, stream>>>(Wq, Wk, Wv, WqT, WkT, WvT, S, zcount);
  qk_kernel<<<dim3(N / 64, B), 256, 0, stream>>>(x, WqT, bq, WkT, bk, Qn, KnT, Ksum);
  s_kernel<<<dim3(C / 64, NT, B), 256, 0, stream>>>(x, KnT, S, xsum);
  matm_kernel<<<dim3(C / 64, 4, B), 256, 0, stream>>>(WvT, bv, S, xsum, Ksum, matM, vsum);
  final_kernel<<<dim3(N / 64, 2, B), 256, 0, stream>>>(x, Qn, Ksum, matM, vsum, gamma, out);
}

// Round 6
// 195.117 us; speedup vs baseline: 1.6769x; 1.6284x over previous
//
#include <hip/hip_runtime.h>
#include <hip/hip_bf16.h>

constexpr int B = 8;
constexpr int C = 512;
constexpr int M = 64;
constexpr int N = 4096;
constexpr float EPS = 1e-6f;
constexpr int NTS = 8;    // n-split for s_kernel -> (8,8,8)=512 blocks
constexpr int LDP = 72;   // bf16 LDS row pitch (144B: 16B-aligned, ~2-way banks on frag reads)
constexpr int LDPF = 68;  // f32 bounce row pitch

typedef __attribute__((ext_vector_type(8))) short short8v;   // 8 bf16 = one MFMA frag
typedef __attribute__((ext_vector_type(4))) short short4v;
typedef __attribute__((ext_vector_type(4))) float f32x4;

__device__ __forceinline__ short f2b(float f) {
  union { __hip_bfloat16 h; short s; } u;
  u.h = __float2bfloat16(f);
  return u.s;
}
__device__ __forceinline__ float b2f(short s) {
  union { __hip_bfloat16 h; short s2; } u;
  u.s2 = s;
  return __bfloat162float(u.h);
}

// ---------------------------------------------------------------------------
// prep: weights f32 -> bf16 (layouts unchanged: Wq/Wk [m][c], Wv [c][c']),
// zero Ksum & xsum accumulators.
// ---------------------------------------------------------------------------
__global__ __launch_bounds__(256) void prep_kernel(
    const float* __restrict__ Wq, const float* __restrict__ Wk,
    const float* __restrict__ Wv, short* __restrict__ Wq_bf,
    short* __restrict__ Wk_bf, short* __restrict__ Wv_bf,
    float* __restrict__ Ksum, float* __restrict__ xsum) {
  const int id = blockIdx.x * 256 + threadIdx.x;
  const int stride = gridDim.x * 256;
  for (int i = id; i < C * M / 4; i += stride) {
    const float4 a = reinterpret_cast<const float4*>(Wq)[i];
    const float4 b = reinterpret_cast<const float4*>(Wk)[i];
    short4v sa = {f2b(a.x), f2b(a.y), f2b(a.z), f2b(a.w)};
    short4v sb = {f2b(b.x), f2b(b.y), f2b(b.z), f2b(b.w)};
    reinterpret_cast<short4v*>(Wq_bf)[i] = sa;
    reinterpret_cast<short4v*>(Wk_bf)[i] = sb;
  }
  for (int i = id; i < C * C / 4; i += stride) {
    const float4 a = reinterpret_cast<const float4*>(Wv)[i];
    short4v sa = {f2b(a.x), f2b(a.y), f2b(a.z), f2b(a.w)};
    reinterpret_cast<short4v*>(Wv_bf)[i] = sa;
  }
  for (int i = id; i < B * M + B * C; i += stride) {
    if (i < B * M) Ksum[i] = 0.f;
    else xsum[i - B * M] = 0.f;
  }
}

// ---------------------------------------------------------------------------
// qk: D[m][n] = Wq/Wk[m][cK] x xT[n][cK] via MFMA; L2-normalize per n;
// writes QnT_bf[b][n][m], Kn_bf[b][m][n]; Ksum via shfl+atomics.
// ---------------------------------------------------------------------------
__global__ __launch_bounds__(256) void qk_kernel(
    const float* __restrict__ x, const short* __restrict__ Wq_bf,
    const float* __restrict__ bq, const short* __restrict__ Wk_bf,
    const float* __restrict__ bk, short* __restrict__ QnT,
    short* __restrict__ KnB, float* __restrict__ Ksum) {
  __shared__ short aq[64 * LDP];        // Wq tile [m][cK]
  __shared__ short ak[64 * LDP];        // Wk tile [m][cK]
  __shared__ short bx[64 * LDP];        // xT tile [n][cK]
  __shared__ float colred[2][4][64];
  __shared__ float rsq[2][64];
  const int t = threadIdx.x;
  const int n0 = blockIdx.x * 64;
  const int b = blockIdx.y;
  const int w = t >> 6, l = t & 63, l15 = l & 15, kg = l >> 4;
  f32x4 accQ[4], accK[4];
#pragma unroll
  for (int i = 0; i < 4; ++i) { accQ[i] = f32x4{0.f, 0.f, 0.f, 0.f}; accK[i] = f32x4{0.f, 0.f, 0.f, 0.f}; }

  for (int c0 = 0; c0 < C; c0 += 64) {
    __syncthreads();
    {  // stage Wq/Wk (bf16, k-contiguous)
      const int m = t >> 2, ko = (t & 3) * 16;
      *reinterpret_cast<short8v*>(&aq[m * LDP + ko]) =
          *reinterpret_cast<const short8v*>(&Wq_bf[m * C + c0 + ko]);
      *reinterpret_cast<short8v*>(&aq[m * LDP + ko + 8]) =
          *reinterpret_cast<const short8v*>(&Wq_bf[m * C + c0 + ko + 8]);
      *reinterpret_cast<short8v*>(&ak[m * LDP + ko]) =
          *reinterpret_cast<const short8v*>(&Wk_bf[m * C + c0 + ko]);
      *reinterpret_cast<short8v*>(&ak[m * LDP + ko + 8]) =
          *reinterpret_cast<const short8v*>(&Wk_bf[m * C + c0 + ko + 8]);
      // stage x with transpose+convert: bx[n][c]
      const int cr = t & 63, ng = t >> 6;
      const float* xg = x + ((size_t)b * C + c0 + cr) * N + n0 + ng * 16;
      float vv[16];
#pragma unroll
      for (int i = 0; i < 4; ++i) {
        const float4 v = *reinterpret_cast<const float4*>(xg + 4 * i);
        vv[4 * i + 0] = v.x; vv[4 * i + 1] = v.y; vv[4 * i + 2] = v.z; vv[4 * i + 3] = v.w;
      }
#pragma unroll
      for (int i = 0; i < 16; ++i) bx[(ng * 16 + i) * LDP + cr] = f2b(vv[i]);
    }
    __syncthreads();
#pragma unroll
    for (int ks = 0; ks < 2; ++ks) {
      const short8v afq = *reinterpret_cast<const short8v*>(&aq[(w * 16 + l15) * LDP + ks * 32 + kg * 8]);
      const short8v afk = *reinterpret_cast<const short8v*>(&ak[(w * 16 + l15) * LDP + ks * 32 + kg * 8]);
#pragma unroll
      for (int tc = 0; tc < 4; ++tc) {
        const short8v bf = *reinterpret_cast<const short8v*>(&bx[(tc * 16 + l15) * LDP + ks * 32 + kg * 8]);
        accQ[tc] = __builtin_amdgcn_mfma_f32_16x16x32_bf16(afq, bf, accQ[tc], 0, 0, 0);
        accK[tc] = __builtin_amdgcn_mfma_f32_16x16x32_bf16(afk, bf, accK[tc], 0, 0, 0);
      }
    }
  }
  // bias (row = w*16 + kg*4 + reg)
  {
    const float4 q4 = *reinterpret_cast<const float4*>(&bq[w * 16 + kg * 4]);
    const float4 k4 = *reinterpret_cast<const float4*>(&bk[w * 16 + kg * 4]);
    const float bqa[4] = {q4.x, q4.y, q4.z, q4.w};
    const float bka[4] = {k4.x, k4.y, k4.z, k4.w};
#pragma unroll
    for (int tc = 0; tc < 4; ++tc)
#pragma unroll
      for (int r = 0; r < 4; ++r) { accQ[tc][r] += bqa[r]; accK[tc][r] += bka[r]; }
  }
  // per-column (n) sum of squares: 16-row wave partial via xor 16,32
#pragma unroll
  for (int tc = 0; tc < 4; ++tc) {
    float vq = accQ[tc][0] * accQ[tc][0] + accQ[tc][1] * accQ[tc][1] +
               accQ[tc][2] * accQ[tc][2] + accQ[tc][3] * accQ[tc][3];
    float vk = accK[tc][0] * accK[tc][0] + accK[tc][1] * accK[tc][1] +
               accK[tc][2] * accK[tc][2] + accK[tc][3] * accK[tc][3];
    vq += __shfl_xor(vq, 16, 64); vq += __shfl_xor(vq, 32, 64);
    vk += __shfl_xor(vk, 16, 64); vk += __shfl_xor(vk, 32, 64);
    if (l < 16) { colred[0][w][tc * 16 + l] = vq; colred[1][w][tc * 16 + l] = vk; }
  }
  __syncthreads();
  if (t < 128) {
    const int which = t >> 6, n = t & 63;
    const float s = colred[which][0][n] + colred[which][1][n] +
                    colred[which][2][n] + colred[which][3][n];
    rsq[which][n] = 1.0f / sqrtf(s);
  }
  __syncthreads();
  // normalize + Ksum row partials
  float ksr[4] = {0.f, 0.f, 0.f, 0.f};
#pragma unroll
  for (int tc = 0; tc < 4; ++tc) {
    const float rq = rsq[0][tc * 16 + l15], rk = rsq[1][tc * 16 + l15];
#pragma unroll
    for (int r = 0; r < 4; ++r) { accQ[tc][r] *= rq; accK[tc][r] *= rk; ksr[r] += accK[tc][r]; }
  }
#pragma unroll
  for (int r = 0; r < 4; ++r) {
    float s = ksr[r];
    s += __shfl_xor(s, 1, 64); s += __shfl_xor(s, 2, 64);
    s += __shfl_xor(s, 4, 64); s += __shfl_xor(s, 8, 64);
    if (l15 == 0) atomicAdd(&Ksum[b * M + w * 16 + kg * 4 + r], s);
  }
  // bounce: QnT into aq [n][m] (b64 writes), Kn into ak [m][n] (b16 writes)
#pragma unroll
  for (int tc = 0; tc < 4; ++tc) {
    short4v q4 = {f2b(accQ[tc][0]), f2b(accQ[tc][1]), f2b(accQ[tc][2]), f2b(accQ[tc][3])};
    *reinterpret_cast<short4v*>(&aq[(tc * 16 + l15) * LDP + w * 16 + kg * 4]) = q4;
#pragma unroll
    for (int r = 0; r < 4; ++r)
      ak[(w * 16 + kg * 4 + r) * LDP + tc * 16 + l15] = f2b(accK[tc][r]);
  }
  __syncthreads();
  {
    const int r = t >> 2, ko = (t & 3) * 16;
    short* qg = QnT + ((size_t)b * N + n0 + r) * M + ko;
    *reinterpret_cast<short8v*>(qg) = *reinterpret_cast<const short8v*>(&aq[r * LDP + ko]);
    *reinterpret_cast<short8v*>(qg + 8) = *reinterpret_cast<const short8v*>(&aq[r * LDP + ko + 8]);
    short* kg2 = KnB + ((size_t)b * M + r) * N + n0 + ko;
    *reinterpret_cast<short8v*>(kg2) = *reinterpret_cast<const short8v*>(&ak[r * LDP + ko]);
    *reinterpret_cast<short8v*>(kg2 + 8) = *reinterpret_cast<const short8v*>(&ak[r * LDP + ko + 8]);
  }
}

// ---------------------------------------------------------------------------
// s: S'[m][c'] = Kn[m][nK] x x[c'][nK] over this block's n-range (materialized
// partials, NO atomics); fuses xsum from the f32 staging values.
// ---------------------------------------------------------------------------
__global__ __launch_bounds__(256) void s_kernel(
    const float* __restrict__ x, const short* __restrict__ KnB,
    float* __restrict__ Spart, float* __restrict__ xsum) {
  __shared__ short sm[2 * 64 * LDP];  // ka | xb ; reused as f32 bounce
  __shared__ float red[256];
  short* ka = sm;
  short* xb = sm + 64 * LDP;
  const int t = threadIdx.x;
  const int c0 = blockIdx.x * 64;
  const int nt = blockIdx.y;
  const int b = blockIdx.z;
  const int w = t >> 6, l = t & 63, l15 = l & 15, kg = l >> 4;
  f32x4 acc[4];
#pragma unroll
  for (int i = 0; i < 4; ++i) acc[i] = f32x4{0.f, 0.f, 0.f, 0.f};
  float xacc = 0.f;
  for (int it = 0; it < (N / NTS) / 64; ++it) {
    const int nk = nt * (N / NTS) + it * 64;
    __syncthreads();
    {
      const int r = t >> 2, ko = (t & 3) * 16;
      *reinterpret_cast<short8v*>(&ka[r * LDP + ko]) =
          *reinterpret_cast<const short8v*>(&KnB[((size_t)b * M + r) * N + nk + ko]);
      *reinterpret_cast<short8v*>(&ka[r * LDP + ko + 8]) =
          *reinterpret_cast<const short8v*>(&KnB[((size_t)b * M + r) * N + nk + ko + 8]);
      const float* xg = x + ((size_t)b * C + c0 + r) * N + nk + ko;
      float vv[16];
#pragma unroll
      for (int i = 0; i < 4; ++i) {
        const float4 v = *reinterpret_cast<const float4*>(xg + 4 * i);
        vv[4 * i] = v.x; vv[4 * i + 1] = v.y; vv[4 * i + 2] = v.z; vv[4 * i + 3] = v.w;
        xacc += v.x + v.y + v.z + v.w;
      }
      short tmp[16];
#pragma unroll
      for (int i = 0; i < 16; ++i) tmp[i] = f2b(vv[i]);
      *reinterpret_cast<short8v*>(&xb[r * LDP + ko]) = *reinterpret_cast<const short8v*>(&tmp[0]);
      *reinterpret_cast<short8v*>(&xb[r * LDP + ko + 8]) = *reinterpret_cast<const short8v*>(&tmp[8]);
    }
    __syncthreads();
#pragma unroll
    for (int ks = 0; ks < 2; ++ks) {
      const short8v af = *reinterpret_cast<const short8v*>(&ka[(w * 16 + l15) * LDP + ks * 32 + kg * 8]);
#pragma unroll
      for (int tc = 0; tc < 4; ++tc) {
        const short8v bf = *reinterpret_cast<const short8v*>(&xb[(tc * 16 + l15) * LDP + ks * 32 + kg * 8]);
        acc[tc] = __builtin_amdgcn_mfma_f32_16x16x32_bf16(af, bf, acc[tc], 0, 0, 0);
      }
    }
  }
  red[t] = xacc;
  __syncthreads();  // also guarantees all frag reads of sm are done
  if (t < 64)
    atomicAdd(&xsum[b * C + c0 + t], red[4 * t] + red[4 * t + 1] + red[4 * t + 2] + red[4 * t + 3]);
  // bounce S' f32 [m][c'] into sm
  float* bo = reinterpret_cast<float*>(sm);
#pragma unroll
  for (int tc = 0; tc < 4; ++tc)
#pragma unroll
    for (int r = 0; r < 4; ++r)
      bo[(w * 16 + kg * 4 + r) * LDPF + tc * 16 + l15] = acc[tc][r];
  __syncthreads();
  {
    const int m = t >> 2, ko = (t & 3) * 16;
    float* gp = Spart + (((size_t)nt * B + b) * M + m) * C + c0 + ko;
#pragma unroll
    for (int i = 0; i < 4; ++i)
      *reinterpret_cast<float4*>(gp + 4 * i) = *reinterpret_cast<const float4*>(&bo[m * LDPF + ko + 4 * i]);
  }
}

// ---------------------------------------------------------------------------
// sreduce: S_bf[b][m][c'] = bf16( sum_nt Spart )
// ---------------------------------------------------------------------------
__global__ __launch_bounds__(256) void sreduce_kernel(const float* __restrict__ Spart,
                                                      short* __restrict__ S_bf) {
  const int i4 = blockIdx.x * 256 + threadIdx.x;  // over B*M*C/4 = 65536
  const size_t stride = (size_t)B * M * C;
  const float* p = Spart + (size_t)i4 * 4;
  float s0 = 0.f, s1 = 0.f, s2 = 0.f, s3 = 0.f;
#pragma unroll
  for (int nt = 0; nt < NTS; ++nt) {
    const float4 v = *reinterpret_cast<const float4*>(p + nt * stride);
    s0 += v.x; s1 += v.y; s2 += v.z; s3 += v.w;
  }
  short4v o = {f2b(s0), f2b(s1), f2b(s2), f2b(s3)};
  *reinterpret_cast<short4v*>(&S_bf[(size_t)i4 * 4]) = o;
}

// ---------------------------------------------------------------------------
// matm: matMT[c][m] = Wv[c][c'K] x S'[m][c'K] + bv[c]*Ksum[m]  (bf16 out)
// fused vsum[b][c] = Wv[c][:]·xsum[b][:] + N*bv[c]
// ---------------------------------------------------------------------------
__global__ __launch_bounds__(256) void matm_kernel(
    const short* __restrict__ Wv_bf, const float* __restrict__ bv,
    const short* __restrict__ S_bf, const float* __restrict__ xsum,
    const float* __restrict__ Ksum, short* __restrict__ matMT,
    float* __restrict__ vsum) {
  __shared__ short wa[64 * LDP];
  __shared__ short sb[64 * LDP];
  __shared__ float xs[64];
  const int t = threadIdx.x;
  const int c0 = blockIdx.x * 64;
  const int b = blockIdx.y;
  const int w = t >> 6, l = t & 63, l15 = l & 15, kg = l >> 4;
  f32x4 acc[4];
#pragma unroll
  for (int i = 0; i < 4; ++i) acc[i] = f32x4{0.f, 0.f, 0.f, 0.f};
  float vacc = 0.f;
  for (int k0 = 0; k0 < C; k0 += 64) {
    __syncthreads();
    {
      const int r = t >> 2, ko = (t & 3) * 16;
      *reinterpret_cast<short8v*>(&wa[r * LDP + ko]) =
          *reinterpret_cast<const short8v*>(&Wv_bf[(size_t)(c0 + r) * C + k0 + ko]);
      *reinterpret_cast<short8v*>(&wa[r * LDP + ko + 8]) =
          *reinterpret_cast<const short8v*>(&Wv_bf[(size_t)(c0 + r) * C + k0 + ko + 8]);
      *reinterpret_cast<short8v*>(&sb[r * LDP + ko]) =
          *reinterpret_cast<const short8v*>(&S_bf[((size_t)b * M + r) * C + k0 + ko]);
      *reinterpret_cast<short8v*>(&sb[r * LDP + ko + 8]) =
          *reinterpret_cast<const short8v*>(&S_bf[((size_t)b * M + r) * C + k0 + ko + 8]);
    }
    if (t < 64) xs[t] = xsum[b * C + k0 + t];
    __syncthreads();
#pragma unroll
    for (int ks = 0; ks < 2; ++ks) {
      const short8v af = *reinterpret_cast<const short8v*>(&wa[(w * 16 + l15) * LDP + ks * 32 + kg * 8]);
#pragma unroll
      for (int tc = 0; tc < 4; ++tc) {
        const short8v bf = *reinterpret_cast<const short8v*>(&sb[(tc * 16 + l15) * LDP + ks * 32 + kg * 8]);
        acc[tc] = __builtin_amdgcn_mfma_f32_16x16x32_bf16(af, bf, acc[tc], 0, 0, 0);
      }
    }
    if (t < 64) {
      float v = 0.f;
#pragma unroll 8
      for (int kk = 0; kk < 64; ++kk) v = fmaf(b2f(wa[t * LDP + kk]), xs[kk], v);
      vacc += v;
    }
  }
  __syncthreads();
  // epilogue: + bv[c]*Ksum[m], bounce bf16 [c][m] into wa
  {
    const float4 b4 = *reinterpret_cast<const float4*>(&bv[c0 + w * 16 + kg * 4]);
    const float bva[4] = {b4.x, b4.y, b4.z, b4.w};
#pragma unroll
    for (int tc = 0; tc < 4; ++tc) {
      const float ksm = Ksum[b * M + tc * 16 + l15];
#pragma unroll
      for (int r = 0; r < 4; ++r)
        wa[(w * 16 + kg * 4 + r) * LDP + tc * 16 + l15] = f2b(acc[tc][r] + bva[r] * ksm);
    }
  }
  __syncthreads();
  {
    const int r = t >> 2, ko = (t & 3) * 16;
    short* gp = matMT + ((size_t)b * C + c0 + r) * M + ko;
    *reinterpret_cast<short8v*>(gp) = *reinterpret_cast<const short8v*>(&wa[r * LDP + ko]);
    *reinterpret_cast<short8v*>(gp + 8) = *reinterpret_cast<const short8v*>(&wa[r * LDP + ko + 8]);
  }
  if (t < 64) vsum[b * C + c0 + t] = vacc + 4096.0f * bv[c0 + t];
}

// ---------------------------------------------------------------------------
// final: D[c][n] = matMT[c][mK] x QnT[n][mK]; out = x + g*tl[n]*(vsum[c]+D)
// tl[n] = 1/(N + sum_m QnT[n][m]*(Ksum[m]+EPS))
// ---------------------------------------------------------------------------
__global__ __launch_bounds__(256) void final_kernel(
    const float* __restrict__ x, const short* __restrict__ QnT,
    const float* __restrict__ Ksum, const short* __restrict__ matMT,
    const float* __restrict__ vsum, const float* __restrict__ gamma,
    float* __restrict__ out) {
  __shared__ short qb[64 * LDP];   // B = QnT [n][m]
  __shared__ short ab[64 * LDP];   // A = matMT [c][m]
  __shared__ float bo[64 * LDPF];  // f32 bounce [c][n]
  __shared__ float ke[64];
  __shared__ float tl[64];
  __shared__ float red2[256];
  const int t = threadIdx.x;
  const int n0 = blockIdx.x * 64;
  const int b = blockIdx.y;
  const int w = t >> 6, l = t & 63, l15 = l & 15, kg = l >> 4;
  {
    const int r = t >> 2, ko = (t & 3) * 16;
    *reinterpret_cast<short8v*>(&qb[r * LDP + ko]) =
        *reinterpret_cast<const short8v*>(&QnT[((size_t)b * N + n0 + r) * M + ko]);
    *reinterpret_cast<short8v*>(&qb[r * LDP + ko + 8]) =
        *reinterpret_cast<const short8v*>(&QnT[((size_t)b * N + n0 + r) * M + ko + 8]);
  }
  if (t < 64) ke[t] = Ksum[b * M + t] + EPS;
  __syncthreads();
  {
    const int n = t & 63, mq = t >> 6;
    float d = 0.f;
#pragma unroll
    for (int j = 0; j < 16; ++j) d = fmaf(b2f(qb[n * LDP + mq * 16 + j]), ke[mq * 16 + j], d);
    red2[t] = d;
  }
  __syncthreads();
  if (t < 64)
    tl[t] = 1.0f / (4096.0f + red2[t] + red2[64 + t] + red2[128 + t] + red2[192 + t]);
  const float g = gamma[0];
  for (int c0 = 0; c0 < C; c0 += 64) {
    __syncthreads();  // prior frag reads of ab + prior store reads of bo done
    {
      const int r = t >> 2, ko = (t & 3) * 16;
      *reinterpret_cast<short8v*>(&ab[r * LDP + ko]) =
          *reinterpret_cast<const short8v*>(&matMT[((size_t)b * C + c0 + r) * M + ko]);
      *reinterpret_cast<short8v*>(&ab[r * LDP + ko + 8]) =
          *reinterpret_cast<const short8v*>(&matMT[((size_t)b * C + c0 + r) * M + ko + 8]);
    }
    __syncthreads();
    f32x4 acc[4];
#pragma unroll
    for (int i = 0; i < 4; ++i) acc[i] = f32x4{0.f, 0.f, 0.f, 0.f};
#pragma unroll
    for (int ks = 0; ks < 2; ++ks) {
      const short8v af = *reinterpret_cast<const short8v*>(&ab[(w * 16 + l15) * LDP + ks * 32 + kg * 8]);
#pragma unroll
      for (int tc = 0; tc < 4; ++tc) {
        const short8v bf = *reinterpret_cast<const short8v*>(&qb[(tc * 16 + l15) * LDP + ks * 32 + kg * 8]);
        acc[tc] = __builtin_amdgcn_mfma_f32_16x16x32_bf16(af, bf, acc[tc], 0, 0, 0);
      }
    }
#pragma unroll
    for (int tc = 0; tc < 4; ++tc)
#pragma unroll
      for (int r = 0; r < 4; ++r)
        bo[(w * 16 + kg * 4 + r) * LDPF + tc * 16 + l15] = acc[tc][r];
    __syncthreads();
    {
      const int r = t >> 2, ko = (t & 3) * 16;
      const int c = c0 + r;
      const float vs = vsum[b * C + c];
      const size_t off = ((size_t)b * C + c) * N + n0 + ko;
#pragma unroll
      for (int i = 0; i < 4; ++i) {
        const float4 xv = *reinterpret_cast<const float4*>(&x[off + 4 * i]);
        const float4 dv = *reinterpret_cast<const float4*>(&bo[r * LDPF + ko + 4 * i]);
        const float4 tv = *reinterpret_cast<const float4*>(&tl[ko + 4 * i]);
        float4 o;
        o.x = xv.x + g * tv.x * (vs + dv.x);
        o.y = xv.y + g * tv.y * (vs + dv.y);
        o.z = xv.z + g * tv.z * (vs + dv.z);
        o.w = xv.w + g * tv.w * (vs + dv.w);
        *reinterpret_cast<float4*>(&out[off + 4 * i]) = o;
      }
    }
  }
}

// ---------------------------------------------------------------------------
extern "C" void kernel_launch(void* const* d_in, const int* in_sizes, int n_in,
                              void* d_out, int out_size, void* d_ws, size_t ws_size,
                              hipStream_t stream) {
  (void)in_sizes; (void)n_in; (void)out_size; (void)ws_size;
  const float* x = (const float*)d_in[0];
  const float* Wq = (const float*)d_in[1];
  const float* bq = (const float*)d_in[2];
  const float* Wk = (const float*)d_in[3];
  const float* bk = (const float*)d_in[4];
  const float* Wv = (const float*)d_in[5];
  const float* bv = (const float*)d_in[6];
  const float* gamma = (const float*)d_in[7];
  float* out = (float*)d_out;

  // ws layout, ~17.7 MB total
  char* wp = (char*)d_ws;
  short* Wq_bf = (short*)wp;            wp += (size_t)C * M * 2;
  short* Wk_bf = (short*)wp;            wp += (size_t)C * M * 2;
  short* Wv_bf = (short*)wp;            wp += (size_t)C * C * 2;
  short* KnB   = (short*)wp;            wp += (size_t)B * M * N * 2;
  short* QnT   = (short*)wp;            wp += (size_t)B * N * M * 2;
  short* S_bf  = (short*)wp;            wp += (size_t)B * M * C * 2;
  short* matMT = (short*)wp;            wp += (size_t)B * C * M * 2;
  float* Spart = (float*)wp;            wp += (size_t)NTS * B * M * C * 4;
  float* Ksum  = (float*)wp;            wp += (size_t)B * M * 4;
  float* xsum  = (float*)wp;            wp += (size_t)B * C * 4;
  float* vsum  = (float*)wp;            wp += (size_t)B * C * 4;

  prep_kernel<<<256, 256, 0, stream>>>(Wq, Wk, Wv, Wq_bf, Wk_bf, Wv_bf, Ksum, xsum);
  qk_kernel<<<dim3(N / 64, B), 256, 0, stream>>>(x, Wq_bf, bq, Wk_bf, bk, QnT, KnB, Ksum);
  s_kernel<<<dim3(C / 64, NTS, B), 256, 0, stream>>>(x, KnB, Spart, xsum);
  sreduce_kernel<<<B * M * C / 4 / 256, 256, 0, stream>>>(Spart, S_bf);
  matm_kernel<<<dim3(C / 64, B), 256, 0, stream>>>(Wv_bf, bv, S_bf, xsum, Ksum, matMT, vsum);
  final_kernel<<<dim3(N / 64, B), 256, 0, stream>>>(x, QnT, Ksum, matMT, vsum, gamma, out);
}